// Round 2
// baseline (253.967 us; speedup 1.0000x reference)
//
#include <hip/hip_runtime.h>

#define ALPHA 0.1f

__global__ __launch_bounds__(256) void loss_fused_kernel(
    const float* __restrict__ preds,
    const float* __restrict__ targets,
    const float* __restrict__ nee_qc,
    const int*   __restrict__ igbp,
    const int*   __restrict__ koppen,
    const float* __restrict__ igbp_table,
    const float* __restrict__ koppen_table,
    float* __restrict__ partial,
    unsigned int* __restrict__ counter,
    float* __restrict__ out,
    float inv_count,
    long long npairs)
{
    __shared__ float s_igbp[16];
    __shared__ float s_kop[8];
    if (threadIdx.x < 16) s_igbp[threadIdx.x] = igbp_table[threadIdx.x];
    if (threadIdx.x < 5)  s_kop[threadIdx.x]  = koppen_table[threadIdx.x];
    __syncthreads();

    float acc = 0.0f;
    const long long stride = (long long)gridDim.x * blockDim.x;
    for (long long j = (long long)blockIdx.x * blockDim.x + threadIdx.x;
         j < npairs; j += stride) {
        // two rows of 6 channels = 12 floats = 3 x float4, 16B-aligned (j*48 bytes)
        const float4* p4 = reinterpret_cast<const float4*>(preds)   + j * 3;
        const float4* t4 = reinterpret_cast<const float4*>(targets) + j * 3;
        float4 pa = p4[0], pb = p4[1], pc = p4[2];
        float4 ta = t4[0], tb = t4[1], tc = t4[2];

        // row 0: channels c0..c5 = pa.x, pa.y, pa.z, pa.w, pb.x, pb.y
        float d0 = pa.x - ta.x, d1 = pa.y - ta.y, d2 = pa.z - ta.z;
        float d3 = pa.w - ta.w, d4 = pb.x - tb.x, d5 = pb.y - tb.y;
        float sse0 = d0*d0 + d1*d1 + d2*d2 + d3*d3 + d4*d4 + d5*d5;
        // balance_error = (p2 - (-(p0-p1)))^2 = (p2 + p0 - p1)^2
        float bal0 = pa.z + (pa.x - pa.y);

        // row 1: channels c0..c5 = pb.z, pb.w, pc.x, pc.y, pc.z, pc.w
        float e0 = pb.z - tb.z, e1 = pb.w - tb.w, e2 = pc.x - tc.x;
        float e3 = pc.y - tc.y, e4 = pc.z - tc.z, e5 = pc.w - tc.w;
        float sse1 = e0*e0 + e1*e1 + e2*e2 + e3*e3 + e4*e4 + e5*e5;
        float bal1 = pc.x + (pb.z - pb.w);

        float2 qc = reinterpret_cast<const float2*>(nee_qc)[j];
        int2   ig = reinterpret_cast<const int2*>(igbp)[j];
        int2   ko = reinterpret_cast<const int2*>(koppen)[j];

        float w0 = qc.x * s_igbp[ig.x] * s_kop[ko.x];
        float w1 = qc.y * s_igbp[ig.y] * s_kop[ko.y];

        acc += sse0 * (1.0f / 6.0f) * w0 + ALPHA * bal0 * bal0;
        acc += sse1 * (1.0f / 6.0f) * w1 + ALPHA * bal1 * bal1;
    }

    // wave-64 shuffle reduce
    #pragma unroll
    for (int off = 32; off > 0; off >>= 1)
        acc += __shfl_down(acc, off, 64);

    __shared__ float s_wave[4];
    __shared__ bool  s_last;
    const int wave = threadIdx.x >> 6;
    const int lane = threadIdx.x & 63;
    if (lane == 0) s_wave[wave] = acc;
    __syncthreads();

    if (threadIdx.x == 0) {
        float bsum = s_wave[0] + s_wave[1] + s_wave[2] + s_wave[3];
        // agent-scope release store: visible across XCDs to the last block
        __hip_atomic_store(&partial[blockIdx.x], bsum,
                           __ATOMIC_RELEASE, __HIP_MEMORY_SCOPE_AGENT);
        unsigned int old = __hip_atomic_fetch_add(counter, 1u,
                           __ATOMIC_ACQ_REL, __HIP_MEMORY_SCOPE_AGENT);
        s_last = (old == gridDim.x - 1);
    }
    __syncthreads();

    if (s_last) {
        // deterministic: fixed-order sum of per-block partials
        float a = 0.0f;
        for (int i = threadIdx.x; i < (int)gridDim.x; i += 256)
            a += __hip_atomic_load(&partial[i],
                                   __ATOMIC_ACQUIRE, __HIP_MEMORY_SCOPE_AGENT);
        #pragma unroll
        for (int off = 32; off > 0; off >>= 1)
            a += __shfl_down(a, off, 64);
        if (lane == 0) s_wave[wave] = a;
        __syncthreads();
        if (threadIdx.x == 0)
            out[0] = (s_wave[0] + s_wave[1] + s_wave[2] + s_wave[3]) * inv_count;
    }
}

extern "C" void kernel_launch(void* const* d_in, const int* in_sizes, int n_in,
                              void* d_out, int out_size, void* d_ws, size_t ws_size,
                              hipStream_t stream) {
    const float* preds        = (const float*)d_in[0];
    const float* targets      = (const float*)d_in[1];
    const float* nee_qc       = (const float*)d_in[2];
    const int*   igbp         = (const int*)d_in[3];
    const int*   koppen       = (const int*)d_in[4];
    const float* igbp_table   = (const float*)d_in[5];
    const float* koppen_table = (const float*)d_in[6];
    float* out     = (float*)d_out;

    float*        partial = (float*)d_ws;
    unsigned int* counter = (unsigned int*)((char*)d_ws + 2048 * sizeof(float));

    const long long BT = (long long)in_sizes[2];   // nee_qc element count = B*T
    const long long npairs = BT / 2;               // B*T is even (16384*365)

    const int block = 256;
    int grid = 2048;                               // 8 blocks/CU on 256 CUs
    long long needed = (npairs + block - 1) / block;
    if (needed < grid) grid = (int)needed;

    // reset the arrival counter each launch (graph-capturable memset node)
    hipMemsetAsync(counter, 0, sizeof(unsigned int), stream);

    loss_fused_kernel<<<grid, block, 0, stream>>>(
        preds, targets, nee_qc, igbp, koppen, igbp_table, koppen_table,
        partial, counter, out, 1.0f / (float)BT, npairs);
}

// Round 3
// 70.024 us; speedup vs baseline: 3.6269x; 3.6269x over previous
//
#include <hip/hip_runtime.h>

#define ALPHA 0.1f

__global__ __launch_bounds__(256) void loss_partial_kernel(
    const float* __restrict__ preds,
    const float* __restrict__ targets,
    const float* __restrict__ nee_qc,
    const int*   __restrict__ igbp,
    const int*   __restrict__ koppen,
    const float* __restrict__ igbp_table,
    const float* __restrict__ koppen_table,
    float* __restrict__ partial,
    long long nquads)
{
    __shared__ float s_igbp[16];
    __shared__ float s_kop[8];
    if (threadIdx.x < 16) s_igbp[threadIdx.x] = igbp_table[threadIdx.x];
    if (threadIdx.x < 5)  s_kop[threadIdx.x]  = koppen_table[threadIdx.x];
    __syncthreads();

    float acc = 0.0f;
    const long long stride = (long long)gridDim.x * blockDim.x;
    for (long long j = (long long)blockIdx.x * blockDim.x + threadIdx.x;
         j < nquads; j += stride) {
        // four rows of 6 channels = 24 floats = 6 x float4 (j*96 bytes, aligned)
        const float4* p4 = reinterpret_cast<const float4*>(preds)   + j * 6;
        const float4* t4 = reinterpret_cast<const float4*>(targets) + j * 6;
        float4 p0 = p4[0], p1 = p4[1], p2 = p4[2], p3 = p4[3], p4v = p4[4], p5 = p4[5];
        float4 t0 = t4[0], t1 = t4[1], t2 = t4[2], t3 = t4[3], t4v = t4[4], t5 = t4[5];

        float4 qc = reinterpret_cast<const float4*>(nee_qc)[j];
        int4   ig = reinterpret_cast<const int4*>(igbp)[j];
        int4   ko = reinterpret_cast<const int4*>(koppen)[j];

        // row 0: c0..c5 = p0.x p0.y p0.z p0.w p1.x p1.y
        {
            float d0 = p0.x - t0.x, d1 = p0.y - t0.y, d2 = p0.z - t0.z;
            float d3 = p0.w - t0.w, d4 = p1.x - t1.x, d5 = p1.y - t1.y;
            float sse = d0*d0 + d1*d1 + d2*d2 + d3*d3 + d4*d4 + d5*d5;
            float bal = p0.z + (p0.x - p0.y);
            float w = qc.x * s_igbp[ig.x] * s_kop[ko.x];
            acc += sse * (1.0f / 6.0f) * w + ALPHA * bal * bal;
        }
        // row 1: c0..c5 = p1.z p1.w p2.x p2.y p2.z p2.w
        {
            float d0 = p1.z - t1.z, d1 = p1.w - t1.w, d2 = p2.x - t2.x;
            float d3 = p2.y - t2.y, d4 = p2.z - t2.z, d5 = p2.w - t2.w;
            float sse = d0*d0 + d1*d1 + d2*d2 + d3*d3 + d4*d4 + d5*d5;
            float bal = p2.x + (p1.z - p1.w);
            float w = qc.y * s_igbp[ig.y] * s_kop[ko.y];
            acc += sse * (1.0f / 6.0f) * w + ALPHA * bal * bal;
        }
        // row 2: c0..c5 = p3.x p3.y p3.z p3.w p4v.x p4v.y
        {
            float d0 = p3.x - t3.x, d1 = p3.y - t3.y, d2 = p3.z - t3.z;
            float d3 = p3.w - t3.w, d4 = p4v.x - t4v.x, d5 = p4v.y - t4v.y;
            float sse = d0*d0 + d1*d1 + d2*d2 + d3*d3 + d4*d4 + d5*d5;
            float bal = p3.z + (p3.x - p3.y);
            float w = qc.z * s_igbp[ig.z] * s_kop[ko.z];
            acc += sse * (1.0f / 6.0f) * w + ALPHA * bal * bal;
        }
        // row 3: c0..c5 = p4v.z p4v.w p5.x p5.y p5.z p5.w
        {
            float d0 = p4v.z - t4v.z, d1 = p4v.w - t4v.w, d2 = p5.x - t5.x;
            float d3 = p5.y - t5.y, d4 = p5.z - t5.z, d5 = p5.w - t5.w;
            float sse = d0*d0 + d1*d1 + d2*d2 + d3*d3 + d4*d4 + d5*d5;
            float bal = p5.x + (p4v.z - p4v.w);
            float w = qc.w * s_igbp[ig.w] * s_kop[ko.w];
            acc += sse * (1.0f / 6.0f) * w + ALPHA * bal * bal;
        }
    }

    // wave-64 shuffle reduce
    #pragma unroll
    for (int off = 32; off > 0; off >>= 1)
        acc += __shfl_down(acc, off, 64);

    __shared__ float s_wave[4];
    const int wave = threadIdx.x >> 6;
    const int lane = threadIdx.x & 63;
    if (lane == 0) s_wave[wave] = acc;
    __syncthreads();
    if (threadIdx.x == 0)
        partial[blockIdx.x] = s_wave[0] + s_wave[1] + s_wave[2] + s_wave[3];
}

__global__ __launch_bounds__(256) void loss_final_kernel(
    const float* __restrict__ partial, int n,
    float* __restrict__ out, float inv_count)
{
    float acc = 0.0f;
    for (int i = threadIdx.x; i < n; i += 256) acc += partial[i];
    #pragma unroll
    for (int off = 32; off > 0; off >>= 1)
        acc += __shfl_down(acc, off, 64);
    __shared__ float s_wave[4];
    const int wave = threadIdx.x >> 6;
    const int lane = threadIdx.x & 63;
    if (lane == 0) s_wave[wave] = acc;
    __syncthreads();
    if (threadIdx.x == 0)
        out[0] = (s_wave[0] + s_wave[1] + s_wave[2] + s_wave[3]) * inv_count;
}

extern "C" void kernel_launch(void* const* d_in, const int* in_sizes, int n_in,
                              void* d_out, int out_size, void* d_ws, size_t ws_size,
                              hipStream_t stream) {
    const float* preds        = (const float*)d_in[0];
    const float* targets      = (const float*)d_in[1];
    const float* nee_qc       = (const float*)d_in[2];
    const int*   igbp         = (const int*)d_in[3];
    const int*   koppen       = (const int*)d_in[4];
    const float* igbp_table   = (const float*)d_in[5];
    const float* koppen_table = (const float*)d_in[6];
    float* out     = (float*)d_out;
    float* partial = (float*)d_ws;

    const long long BT = (long long)in_sizes[2];   // nee_qc element count = B*T
    const long long nquads = BT / 4;               // B*T divisible by 4 (16384*365)

    const int block = 256;
    int grid = 2048;                               // 8 blocks/CU on 256 CUs
    long long needed = (nquads + block - 1) / block;
    if (needed < grid) grid = (int)needed;

    loss_partial_kernel<<<grid, block, 0, stream>>>(
        preds, targets, nee_qc, igbp, koppen, igbp_table, koppen_table,
        partial, nquads);
    loss_final_kernel<<<1, 256, 0, stream>>>(partial, grid, out,
                                             1.0f / (float)BT);
}

// Round 4
// 65.892 us; speedup vs baseline: 3.8543x; 1.0627x over previous
//
#include <hip/hip_runtime.h>

#define ALPHA 0.1f

__global__ __launch_bounds__(256) void loss_partial_kernel(
    const float* __restrict__ preds,
    const float* __restrict__ targets,
    const float* __restrict__ nee_qc,
    const int*   __restrict__ igbp,
    const int*   __restrict__ koppen,
    const float* __restrict__ igbp_table,
    const float* __restrict__ koppen_table,
    float* __restrict__ partial,
    long long npairs)
{
    __shared__ float s_igbp[16];
    __shared__ float s_kop[8];
    if (threadIdx.x < 16) s_igbp[threadIdx.x] = igbp_table[threadIdx.x];
    if (threadIdx.x < 5)  s_kop[threadIdx.x]  = koppen_table[threadIdx.x];
    __syncthreads();

    float acc = 0.0f;
    const long long stride = (long long)gridDim.x * blockDim.x;
    for (long long j = (long long)blockIdx.x * blockDim.x + threadIdx.x;
         j < npairs; j += stride) {
        // two rows of 6 channels = 12 floats = 3 x float4, 16B-aligned (j*48 bytes)
        const float4* p4 = reinterpret_cast<const float4*>(preds)   + j * 3;
        const float4* t4 = reinterpret_cast<const float4*>(targets) + j * 3;
        float4 pa = p4[0], pb = p4[1], pc = p4[2];
        float4 ta = t4[0], tb = t4[1], tc = t4[2];

        // row 0: channels c0..c5 = pa.x, pa.y, pa.z, pa.w, pb.x, pb.y
        float d0 = pa.x - ta.x, d1 = pa.y - ta.y, d2 = pa.z - ta.z;
        float d3 = pa.w - ta.w, d4 = pb.x - tb.x, d5 = pb.y - tb.y;
        float sse0 = d0*d0 + d1*d1 + d2*d2 + d3*d3 + d4*d4 + d5*d5;
        // balance_error = (p2 - (-(p0-p1)))^2 = (p2 + p0 - p1)^2
        float bal0 = pa.z + (pa.x - pa.y);

        // row 1: channels c0..c5 = pb.z, pb.w, pc.x, pc.y, pc.z, pc.w
        float e0 = pb.z - tb.z, e1 = pb.w - tb.w, e2 = pc.x - tc.x;
        float e3 = pc.y - tc.y, e4 = pc.z - tc.z, e5 = pc.w - tc.w;
        float sse1 = e0*e0 + e1*e1 + e2*e2 + e3*e3 + e4*e4 + e5*e5;
        float bal1 = pc.x + (pb.z - pb.w);

        float2 qc = reinterpret_cast<const float2*>(nee_qc)[j];
        int2   ig = reinterpret_cast<const int2*>(igbp)[j];
        int2   ko = reinterpret_cast<const int2*>(koppen)[j];

        float w0 = qc.x * s_igbp[ig.x] * s_kop[ko.x];
        float w1 = qc.y * s_igbp[ig.y] * s_kop[ko.y];

        acc += sse0 * (1.0f / 6.0f) * w0 + ALPHA * bal0 * bal0;
        acc += sse1 * (1.0f / 6.0f) * w1 + ALPHA * bal1 * bal1;
    }

    // wave-64 shuffle reduce
    #pragma unroll
    for (int off = 32; off > 0; off >>= 1)
        acc += __shfl_down(acc, off, 64);

    __shared__ float s_wave[4];
    const int wave = threadIdx.x >> 6;
    const int lane = threadIdx.x & 63;
    if (lane == 0) s_wave[wave] = acc;
    __syncthreads();
    if (threadIdx.x == 0)
        partial[blockIdx.x] = s_wave[0] + s_wave[1] + s_wave[2] + s_wave[3];
}

__global__ __launch_bounds__(256) void loss_final_kernel(
    const float* __restrict__ partial, int n,
    float* __restrict__ out, float inv_count)
{
    float acc = 0.0f;
    for (int i = threadIdx.x; i < n; i += 256) acc += partial[i];
    #pragma unroll
    for (int off = 32; off > 0; off >>= 1)
        acc += __shfl_down(acc, off, 64);
    __shared__ float s_wave[4];
    const int wave = threadIdx.x >> 6;
    const int lane = threadIdx.x & 63;
    if (lane == 0) s_wave[wave] = acc;
    __syncthreads();
    if (threadIdx.x == 0)
        out[0] = (s_wave[0] + s_wave[1] + s_wave[2] + s_wave[3]) * inv_count;
}

extern "C" void kernel_launch(void* const* d_in, const int* in_sizes, int n_in,
                              void* d_out, int out_size, void* d_ws, size_t ws_size,
                              hipStream_t stream) {
    const float* preds        = (const float*)d_in[0];
    const float* targets      = (const float*)d_in[1];
    const float* nee_qc       = (const float*)d_in[2];
    const int*   igbp         = (const int*)d_in[3];
    const int*   koppen       = (const int*)d_in[4];
    const float* igbp_table   = (const float*)d_in[5];
    const float* koppen_table = (const float*)d_in[6];
    float* out     = (float*)d_out;
    float* partial = (float*)d_ws;

    const long long BT = (long long)in_sizes[2];   // nee_qc element count = B*T
    const long long npairs = BT / 2;               // B*T is even (16384*365)

    const int block = 256;
    int grid = 2048;                               // 8 blocks/CU on 256 CUs
    long long needed = (npairs + block - 1) / block;
    if (needed < grid) grid = (int)needed;

    loss_partial_kernel<<<grid, block, 0, stream>>>(
        preds, targets, nee_qc, igbp, koppen, igbp_table, koppen_table,
        partial, npairs);
    loss_final_kernel<<<1, 256, 0, stream>>>(partial, grid, out,
                                             1.0f / (float)BT);
}